// Round 14
// baseline (146.647 us; speedup 1.0000x reference)
//
#include <hip/hip_runtime.h>
#include <math.h>

// DiffKS round 17.
// r16 (serial 82.7) confirmed the owner VALU stream is the critical path at
// ~8 cy/issued-instr; shrinking it still pays. r17 packs the dot product:
//   * v_pk_fma_f32 (CDNA VOP3P, 2xf32/instr) via __builtin_elementwise_fma
//     on ext_vector float2 - coef pairs (m2j,m2j+1) are already aligned
//     VGPR pairs (pa0.xy/.zw, pa1.xy/.zw) and each history float2 load is
//     the matching operand pair;
//   * per sample: 4 pk_fma (even/odd dual accumulator seeded {x,0}) + 1
//     cross-add; owner body VALU 17 -> 10, total 27 -> 20 instrs;
//   * same reassociation class r16 already passed (absmax 0.00098).
// Everything else identical to r16 (r14 structure + 5-lane boundary chain).
// Stop rule: serial >= 80us => converged.

#define T_SAMPLES 44100
#define NFRAMES   100
#define NCOEF     6
#define BURST     2048
#define EXC_ORD   5

#define HISTSZ    2120          // 2048 ring + 64 dump slots + pad
#define GRPF      9600          // 800 samples * 12 floats per group
#define CFBUF     9856          // 9728 staged (38x1KB) + 128 pad for reads
#define POOLF     32448         // 3*CFBUF (29568) / phase-1 overlay (32448)

#define WS_COEF_FLOATS (T_SAMPLES * 12)
#define WS_EXC_OFF     WS_COEF_FLOATS
#define WS_EXC_FLOATS  (EXC_ORD * BURST)
#define WS_TOTAL_BYTES ((size_t)(WS_COEF_FLOATS + WS_EXC_FLOATS) * 4)

typedef float f32x2 __attribute__((ext_vector_type(2)));

// ---------------------------------------------------------------- kernel A
__global__ __launch_bounds__(256) void diffks_precompute(
    const float* __restrict__ delay_frames,
    const float* __restrict__ raw_coeff,
    const float* __restrict__ raw_gain,
    const float* __restrict__ exc_coeff,
    float* __restrict__ ws)
{
    int g = blockIdx.x * 256 + threadIdx.x;
    const float gain = 0.1f / (1.0f + expf(-raw_gain[0])) + 0.9f;

    if (g < T_SAMPLES) {
        const float stepT = 99.0f / (float)(T_SAMPLES - 1);
        float pos = (float)g * stepT;
        int i0 = (int)pos; if (i0 > NFRAMES - 2) i0 = NFRAMES - 2;
        float w = pos - (float)i0;

        float d0 = delay_frames[i0], d1 = delay_frames[i0 + 1];
        float delay = d0 + (d1 - d0) * w;
        int z = (int)delay;                  // delay >= 100 > 0
        float alfa = delay - (float)z;

        float b[NCOEF];
        {
            float c0v[NCOEF], c1v[NCOEF];
            float s0 = 0.f, s1 = 0.f;
            #pragma unroll
            for (int j = 0; j < NCOEF; ++j) {
                c0v[j] = 1.0f / (1.0f + expf(-raw_coeff[i0 * NCOEF + j]));
                c1v[j] = 1.0f / (1.0f + expf(-raw_coeff[(i0 + 1) * NCOEF + j]));
                s0 += c0v[j]; s1 += c1v[j];
            }
            float g0 = gain / s0, g1 = gain / s1;
            #pragma unroll
            for (int j = 0; j < NCOEF; ++j) {
                float x0 = c0v[j] * g0, x1 = c1v[j] * g1;
                b[j] = x0 + (x1 - x0) * w;
            }
        }
        // v_j exactly as previous rounds (bit-identical), then negate (exact)
        float oma = 1.0f - alfa;
        float v0 = -oma * b[0];
        float v1 = -(alfa * b[0] + oma * b[1]);
        float v2 = -(alfa * b[1] + oma * b[2]);
        float v3 = -(alfa * b[2] + oma * b[3]);
        float v4 = -(alfa * b[3] + oma * b[4]);
        float v5 = -(alfa * b[4] + oma * b[5]);
        float v6 = -alfa * b[5];
        float pv0 = -v0, pv1 = -v1, pv2 = -v2, pv3 = -v3;
        float pv4 = -v4, pv5 = -v5, pv6 = -v6;

        int base = g - z - 1;
        int q = base - 6;                    // window = y[q .. q+6]
        int off = q & 1;
        unsigned b2 = ((unsigned)q) & 2046u; // (q & ~1) & 2047, 8B-aligned

        // shifted taps: m[off+6-j] = pv_j  (FMA iterates i = 7..0)
        float m0, m1, m2, m3, m4, m5, m6, m7;
        if (off) { m0 = 0.f; m1 = pv6; m2 = pv5; m3 = pv4;
                   m4 = pv3; m5 = pv2; m6 = pv1; m7 = pv0; }
        else     { m0 = pv6; m1 = pv5; m2 = pv4; m3 = pv3;
                   m4 = pv2; m5 = pv1; m6 = pv0; m7 = 0.f; }

        float4* o = (float4*)(ws + (size_t)g * 12);
        o[0] = make_float4(m0, m1, m2, m3);
        o[1] = make_float4(m4, m5, m6, m7);
        o[2] = make_float4(__int_as_float((int)b2), 0.f, 0.f, 0.f);
    } else if (g < T_SAMPLES + BURST) {
        int te = g - T_SAMPLES;
        const float stepE = 99.0f / (float)(BURST - 1);
        float pos = (float)te * stepE;
        int i0 = (int)pos; if (i0 > NFRAMES - 2) i0 = NFRAMES - 2;
        float w = pos - (float)i0;
        float* o = ws + WS_EXC_OFF + te * EXC_ORD;     // interleaved [t*5+k]
        #pragma unroll
        for (int k = 0; k < EXC_ORD; ++k) {
            float a0 = exc_coeff[i0 * EXC_ORD + k];
            float a1 = exc_coeff[(i0 + 1) * EXC_ORD + k];
            o[k] = a0 + (a1 - a0) * w;
        }
    }
}

// async global->LDS copy, 16B per lane; LDS base must be wave-uniform
__device__ __forceinline__ void gload_lds16(const float* g, float* l) {
    __builtin_amdgcn_global_load_lds(
        (const __attribute__((address_space(1))) unsigned int*)(g),
        (__attribute__((address_space(3))) unsigned int*)(l),
        16, 0, 0);
}

// ---------------------------------------------------------------- kernel B
__global__ __launch_bounds__(256, 1) void diffks_serial(
    const float* __restrict__ excitation,
    const float* __restrict__ ws,
    float* __restrict__ out)
{
    __shared__ float s_pool[POOLF];      // 3 coef buffers / phase-1 overlay
    __shared__ float s_x[64][33];        // burst (padded rows)
    __shared__ float s_hist[HISTSZ];     // 2048 ring + 64 dump

    // phase-1 arrays overlay coef buffer 2 region (phase 1 ends before use)
    float (* const s_a)[161]   = (float(*)[161])(s_pool + 19712);
    float (* const s_tail)[32] = (float(*)[32])(s_pool + 30016);
    float (* const s_bound)[6] = (float(*)[6])(s_pool + 32064);

    const int tid  = threadIdx.x;
    const int lane = tid & 63;
    const int wv   = tid >> 6;

    // ---- stage (all 256 threads) ----
    for (int t = tid; t < BURST; t += 256)
        s_x[t >> 5][t & 31] = excitation[t];
    for (int i = 0; i < 8; ++i) {        // exc coefs, 5 contiguous scalars
        int t = tid + i * 256;
        const float* g = ws + WS_EXC_OFF + t * EXC_ORD;
        float* dst = &s_a[t >> 5][(t & 31) * 5];
        dst[0] = g[0]; dst[1] = g[1]; dst[2] = g[2];
        dst[3] = g[3]; dst[4] = g[4];
    }
    for (int i = tid; i < HISTSZ; i += 256) s_hist[i] = 0.0f;
    __syncthreads();

    // ---- phase 1: excitation LPC via 64-segment state-space scan (wave 0) --
    if (tid < 64) {
        float st[6][5];
        #pragma unroll
        for (int r = 0; r < 6; ++r)
            #pragma unroll
            for (int k = 0; k < 5; ++k) st[r][k] = 0.0f;
        #pragma unroll
        for (int r = 1; r <= 5; ++r) st[r][r - 1] = 1.0f;

        const float* ar = &s_a[lane][0];
        const float* xr = &s_x[lane][0];
        #pragma unroll 8
        for (int i = 0; i < 32; ++i) {
            float a0 = ar[i * 5 + 0], a1 = ar[i * 5 + 1], a2 = ar[i * 5 + 2];
            float a3 = ar[i * 5 + 3], a4 = ar[i * 5 + 4];
            float xv = xr[i];
            #pragma unroll
            for (int r = 0; r < 6; ++r) {
                float acc = (r == 0) ? xv : 0.0f;
                acc = fmaf(-a0, st[r][0], acc);
                acc = fmaf(-a1, st[r][1], acc);
                acc = fmaf(-a2, st[r][2], acc);
                acc = fmaf(-a3, st[r][3], acc);
                acc = fmaf(-a4, st[r][4], acc);
                st[r][4] = st[r][3]; st[r][3] = st[r][2];
                st[r][2] = st[r][1]; st[r][1] = st[r][0];
                st[r][0] = acc;
            }
        }
        #pragma unroll
        for (int r = 0; r < 6; ++r)
            #pragma unroll
            for (int k = 0; k < 5; ++k)
                s_tail[lane][r * 5 + k] = st[r][k];
    }
    __syncthreads();

    if (tid < 5) {   // boundary chain: 5 lanes, one output component each
        float Yk = 0.0f;
        for (int l = 0; l < 64; ++l) {
            s_bound[l][tid] = Yk;
            float y0 = __shfl(Yk, 0);
            float y1 = __shfl(Yk, 1);
            float y2 = __shfl(Yk, 2);
            float y3 = __shfl(Yk, 3);
            float y4 = __shfl(Yk, 4);
            const float* tl = &s_tail[l][0];
            float acc = tl[tid];
            acc = fmaf(tl[5 + tid],  y0, acc);
            acc = fmaf(tl[10 + tid], y1, acc);
            acc = fmaf(tl[15 + tid], y2, acc);
            acc = fmaf(tl[20 + tid], y3, acc);
            acc = fmaf(tl[25 + tid], y4, acc);
            Yk = acc;
        }
    }
    __syncthreads();

    if (tid < 64) {   // re-run each segment with correct boundary state
        float b0 = s_bound[lane][0], b1 = s_bound[lane][1], b2 = s_bound[lane][2];
        float b3 = s_bound[lane][3], b4 = s_bound[lane][4];
        const float* ar = &s_a[lane][0];
        float* xr = &s_x[lane][0];
        #pragma unroll 8
        for (int i = 0; i < 32; ++i) {
            float a0 = ar[i * 5 + 0], a1 = ar[i * 5 + 1], a2 = ar[i * 5 + 2];
            float a3 = ar[i * 5 + 3], a4 = ar[i * 5 + 4];
            float acc = xr[i];
            acc = fmaf(-a0, b0, acc);
            acc = fmaf(-a1, b1, acc);
            acc = fmaf(-a2, b2, acc);
            acc = fmaf(-a3, b3, acc);
            acc = fmaf(-a4, b4, acc);
            b4 = b3; b3 = b2; b2 = b1; b1 = b0; b0 = acc;
            xr[i] = acc;
        }
    }
    __syncthreads();    // phase 1 done; s_pool free for the 3 coef buffers

    // ---- phase 2: 4-wave round-robin, 8 bodies/step, 8 prepped reg sets ----
    const bool lane_act = (lane < 50);
    const unsigned dumpA = 2048u + (unsigned)lane;   // per-lane dump slot

    #define STAGE_GRP(gg)                                                      \
    {                                                                          \
        float* dstb = s_pool + ((unsigned)(gg) % 3u) * CFBUF;                  \
        const float* srcb = ws + (size_t)(gg) * GRPF + lane * 4;               \
        const int nis = ((gg) >= 55) ? 5 : 38;                                 \
        for (int i = 0; i < nis; ++i)                                          \
            gload_lds16(srcb + i * 256, dstb + i * 256);                       \
    }

    // 8 register sets, all statically named (~184 VGPR; 1 wave/SIMD has 512)
    #define DECLSET(J)                                                         \
        float4 p##J##a0, p##J##a1, p##J##b0, p##J##b1;                         \
        unsigned u##J##A0, u##J##A1, u##J##A2, u##J##A3;                       \
        unsigned u##J##B0, u##J##B1, u##J##B2, u##J##B3;                       \
        unsigned w##J##A, w##J##B;                                             \
        float x##J##A, x##J##B;
    DECLSET(0) DECLSET(1) DECLSET(2) DECLSET(3)
    DECLSET(4) DECLSET(5) DECLSET(6) DECLSET(7)
    #undef DECLSET

    #define PREPJ(J, BB, WXF)                                                  \
    {                                                                          \
        int b_ = (BB); if (b_ > 440) b_ = 440;                                 \
        const float* bu_ = s_pool + ((unsigned)(b_ >> 3) % 3u) * CFBUF;        \
        const int ln_ = (b_ & 7) * 100 + lane;                                 \
        const float4* qA_ = (const float4*)(bu_ + ln_ * 12);                   \
        const float4* qB_ = (const float4*)(bu_ + (ln_ + 50) * 12);            \
        p##J##a0 = qA_[0]; p##J##a1 = qA_[1];                                  \
        const unsigned bA_ = (unsigned)__float_as_int(qA_[2].x);               \
        p##J##b0 = qB_[0]; p##J##b1 = qB_[1];                                  \
        const unsigned bB_ = (unsigned)__float_as_int(qB_[2].x);               \
        u##J##A0 = bA_;               u##J##B0 = bB_;                          \
        u##J##A1 = (bA_ + 2) & 2047u; u##J##B1 = (bB_ + 2) & 2047u;            \
        u##J##A2 = (bA_ + 4) & 2047u; u##J##B2 = (bB_ + 4) & 2047u;            \
        u##J##A3 = (bA_ + 6) & 2047u; u##J##B3 = (bB_ + 6) & 2047u;            \
        const int tA_ = b_ * 100 + lane;                                       \
        const int tB_ = tA_ + 50;                                              \
        if (WXF) {                                                             \
            x##J##A = (lane_act && tA_ < BURST)                                \
                          ? s_x[(tA_ >> 5) & 63][tA_ & 31] : 0.0f;             \
            x##J##B = (lane_act && tB_ < BURST)                                \
                          ? s_x[(tB_ >> 5) & 63][tB_ & 31] : 0.0f;             \
        } else { x##J##A = 0.0f; x##J##B = 0.0f; }                             \
        w##J##A = lane_act ? (((unsigned)tA_) & 2047u) : dumpA;                \
        w##J##B = lane_act ? (((unsigned)tB_) & 2047u) : dumpA;                \
    }

    #define PREPALL(SS, WXF)                                                   \
    {                                                                          \
        const int nb_ = (SS) * 8;                                              \
        PREPJ(0, nb_ + 0, WXF) PREPJ(1, nb_ + 1, WXF)                          \
        PREPJ(2, nb_ + 2, WXF) PREPJ(3, nb_ + 3, WXF)                          \
        PREPJ(4, nb_ + 4, WXF) PREPJ(5, nb_ + 5, WXF)                          \
        PREPJ(6, nb_ + 6, WXF) PREPJ(7, nb_ + 7, WXF)                          \
    }

    // one body: 8 ds_read -> 4 packed fma per sample (even/odd dual acc
    // seeded {x,0}) -> cross-add -> 2 ds_write. v_pk_fma_f32 via
    // __builtin_elementwise_fma on float2 vectors.
    #define CBODY(J)                                                           \
    {                                                                          \
        const float2 a01_ = *(const float2*)(s_hist + u##J##A0);               \
        const float2 b01_ = *(const float2*)(s_hist + u##J##B0);               \
        const float2 a23_ = *(const float2*)(s_hist + u##J##A1);               \
        const float2 b23_ = *(const float2*)(s_hist + u##J##B1);               \
        const float2 a45_ = *(const float2*)(s_hist + u##J##A2);               \
        const float2 b45_ = *(const float2*)(s_hist + u##J##B2);               \
        const float2 a67_ = *(const float2*)(s_hist + u##J##A3);               \
        const float2 b67_ = *(const float2*)(s_hist + u##J##B3);               \
        f32x2 accA = {x##J##A, 0.0f};                                          \
        f32x2 accB = {x##J##B, 0.0f};                                          \
        {                                                                      \
            f32x2 m_, h_;                                                      \
            m_ = (f32x2){p##J##a0.x, p##J##a0.y};                              \
            h_ = (f32x2){a01_.x, a01_.y};                                      \
            accA = __builtin_elementwise_fma(m_, h_, accA);                    \
            m_ = (f32x2){p##J##b0.x, p##J##b0.y};                              \
            h_ = (f32x2){b01_.x, b01_.y};                                      \
            accB = __builtin_elementwise_fma(m_, h_, accB);                    \
            m_ = (f32x2){p##J##a0.z, p##J##a0.w};                              \
            h_ = (f32x2){a23_.x, a23_.y};                                      \
            accA = __builtin_elementwise_fma(m_, h_, accA);                    \
            m_ = (f32x2){p##J##b0.z, p##J##b0.w};                              \
            h_ = (f32x2){b23_.x, b23_.y};                                      \
            accB = __builtin_elementwise_fma(m_, h_, accB);                    \
            m_ = (f32x2){p##J##a1.x, p##J##a1.y};                              \
            h_ = (f32x2){a45_.x, a45_.y};                                      \
            accA = __builtin_elementwise_fma(m_, h_, accA);                    \
            m_ = (f32x2){p##J##b1.x, p##J##b1.y};                              \
            h_ = (f32x2){b45_.x, b45_.y};                                      \
            accB = __builtin_elementwise_fma(m_, h_, accB);                    \
            m_ = (f32x2){p##J##a1.z, p##J##a1.w};                              \
            h_ = (f32x2){a67_.x, a67_.y};                                      \
            accA = __builtin_elementwise_fma(m_, h_, accA);                    \
            m_ = (f32x2){p##J##b1.z, p##J##b1.w};                              \
            h_ = (f32x2){b67_.x, b67_.y};                                      \
            accB = __builtin_elementwise_fma(m_, h_, accB);                    \
        }                                                                      \
        s_hist[w##J##A] = accA.x + accA.y;                                     \
        s_hist[w##J##B] = accB.x + accB.y;                                     \
    }

    // one super-step: owner computes 8 bodies; stager issues group ss+2;
    // dumper stores previous step's 800 samples; prepper drains own vmcnt
    // and preps ALL of step ss+1.
    #define STEPBODY(WXF)                                                      \
    {                                                                          \
        if (wv == (ss & 3)) {                                                  \
            CBODY(0) CBODY(1) CBODY(2) CBODY(3)                                \
            CBODY(4) CBODY(5) CBODY(6) CBODY(7)                                \
        }                                                                      \
        if ((ss <= 53) && (wv == ((ss + 2) & 3))) { STAGE_GRP(ss + 2) }        \
        if ((ss >= 1) && (wv == ((ss + 3) & 3))) {                             \
            const int t0_ = (ss - 1) * 800;                                    \
            _Pragma("unroll")                                                  \
            for (int i_ = 0; i_ < 12; ++i_) {                                  \
                int t_ = t0_ + i_ * 64 + lane;                                 \
                out[t_] = s_hist[((unsigned)t_) & 2047u];                      \
            }                                                                  \
            { int t_ = t0_ + 768 + lane;                                       \
              if (lane < 32) out[t_] = s_hist[((unsigned)t_) & 2047u]; }       \
        }                                                                      \
        if (wv == ((ss + 1) & 3)) {                                            \
            asm volatile("s_waitcnt vmcnt(0)" ::: "memory");                   \
            PREPALL(ss + 1, WXF)                                               \
        }                                                                      \
        asm volatile("s_waitcnt lgkmcnt(0)\n\ts_barrier" ::: "memory");        \
    }

    // prologue: wave 0 stages+drains group 0 and preps step 0 (bodies 0..7);
    // wave 1 stages group 1 (drains own vmcnt at step 0 as prepper).
    if (wv == 0) {
        STAGE_GRP(0)
        asm volatile("s_waitcnt vmcnt(0)" ::: "memory");
    }
    if (wv == 1) { STAGE_GRP(1) }
    __syncthreads();
    if (wv == 0) { PREPALL(0, true) }
    __syncthreads();

    // steps 0..1: preps still excitation-active (bodies 8..23 cover body 20)
    #pragma unroll 1
    for (int ss = 0; ss < 2; ++ss) STEPBODY(true)
    // steps 2..54: steady state (prepped bodies >= 24, t >= 2400 > 2047)
    #pragma unroll 1
    for (int ss = 2; ss < 55; ++ss) STEPBODY(false)

    // tail body 440 (step 55, owner wave 3, set 0 prepped at step 54)
    if (wv == 3) { CBODY(0) }
    asm volatile("s_waitcnt lgkmcnt(0)\n\ts_barrier" ::: "memory");
    // final dump: samples [43200, 44100)
    for (int t_ = 43200 + tid; t_ < T_SAMPLES; t_ += 256)
        out[t_] = s_hist[((unsigned)t_) & 2047u];

    #undef STEPBODY
    #undef CBODY
    #undef PREPALL
    #undef PREPJ
    #undef STAGE_GRP
}

// ------------------------------------------------- fallback (round-1 kernel)
#define CHUNK_FB  101
#define NCH_FB    ((T_SAMPLES + CHUNK_FB - 1) / CHUNK_FB)
#define HIST_FB   1024

__global__ __launch_bounds__(128) void diffks_fallback(
    const float* __restrict__ delay_frames,
    const float* __restrict__ excitation,
    const float* __restrict__ raw_coeff,
    const float* __restrict__ raw_gain,
    const float* __restrict__ exc_coeff,
    float* __restrict__ out)
{
    __shared__ float s_a[EXC_ORD][BURST];
    __shared__ float s_x[BURST];
    __shared__ float s_hist[HIST_FB];
    __shared__ __align__(16) float s_coef[NFRAMES][8];
    __shared__ float s_delay[NFRAMES];

    const int tid = threadIdx.x;
    const float gain = 0.1f / (1.0f + expf(-raw_gain[0])) + 0.9f;

    for (int i = tid; i < NFRAMES; i += 128) s_delay[i] = delay_frames[i];
    for (int f = tid; f < NFRAMES; f += 128) {
        float sb[NCOEF]; float s = 0.0f;
        #pragma unroll
        for (int j = 0; j < NCOEF; ++j) {
            sb[j] = 1.0f / (1.0f + expf(-raw_coeff[f * NCOEF + j]));
            s += sb[j];
        }
        float inv = gain / s;
        #pragma unroll
        for (int j = 0; j < NCOEF; ++j) s_coef[f][j] = sb[j] * inv;
        s_coef[f][6] = 0.0f; s_coef[f][7] = 0.0f;
    }
    const float stepE = 99.0f / 2047.0f;
    for (int t = tid; t < BURST; t += 128) {
        float pos = (float)t * stepE;
        int i0 = (int)pos; if (i0 > NFRAMES - 2) i0 = NFRAMES - 2;
        float w = pos - (float)i0;
        const float* c0 = exc_coeff + i0 * EXC_ORD;
        #pragma unroll
        for (int k = 0; k < EXC_ORD; ++k) {
            float a0 = c0[k], a1 = c0[k + EXC_ORD];
            s_a[k][t] = a0 + (a1 - a0) * w;
        }
        s_x[t] = excitation[t];
    }
    for (int i = tid; i < HIST_FB; i += 128) s_hist[i] = 0.0f;
    __syncthreads();

    if (tid == 0) {
        float y1 = 0.f, y2 = 0.f, y3 = 0.f, y4 = 0.f, y5 = 0.f;
        #pragma unroll 4
        for (int t = 0; t < BURST; ++t) {
            float p = s_x[t];
            p = fmaf(-s_a[1][t], y2, p);
            p = fmaf(-s_a[2][t], y3, p);
            p = fmaf(-s_a[3][t], y4, p);
            p = fmaf(-s_a[4][t], y5, p);
            float y = fmaf(-s_a[0][t], y1, p);
            s_x[t] = y;
            y5 = y4; y4 = y3; y3 = y2; y2 = y1; y1 = y;
        }
    }
    __syncthreads();

    const float stepT = 99.0f / (float)(T_SAMPLES - 1);
    for (int c = 0; c < NCH_FB; ++c) {
        int t = c * CHUNK_FB + tid;
        if (tid < CHUNK_FB && t < T_SAMPLES) {
            float pos = (float)t * stepT;
            int i0 = (int)pos; if (i0 > NFRAMES - 2) i0 = NFRAMES - 2;
            float w = pos - (float)i0;
            float d0 = s_delay[i0], d1 = s_delay[i0 + 1];
            float delay = d0 + (d1 - d0) * w;
            int z = (int)delay;
            float alfa = delay - (float)z;
            const float4* f0 = reinterpret_cast<const float4*>(s_coef[i0]);
            const float4* f1 = reinterpret_cast<const float4*>(s_coef[i0 + 1]);
            float4 c0a = f0[0], c0b = f0[1];
            float4 c1a = f1[0], c1b = f1[1];
            float b[NCOEF];
            b[0] = c0a.x + (c1a.x - c0a.x) * w;
            b[1] = c0a.y + (c1a.y - c0a.y) * w;
            b[2] = c0a.z + (c1a.z - c0a.z) * w;
            b[3] = c0a.w + (c1a.w - c0a.w) * w;
            b[4] = c0b.x + (c1b.x - c0b.x) * w;
            b[5] = c0b.y + (c1b.y - c0b.y) * w;
            float oma = 1.0f - alfa;
            float v[7];
            v[0] = -oma * b[0];
            #pragma unroll
            for (int j = 1; j <= 5; ++j) v[j] = -(alfa * b[j - 1] + oma * b[j]);
            v[6] = -alfa * b[5];
            float x = (t < BURST) ? s_x[t] : 0.0f;
            int base = t - z - 1;
            float sum = 0.0f;
            #pragma unroll
            for (int j = 0; j < 7; ++j) {
                int idx = base - j;
                float yv = s_hist[idx & (HIST_FB - 1)];
                if (idx < 0) yv = 0.0f;
                sum = fmaf(v[j], yv, sum);
            }
            float y = x - sum;
            s_hist[t & (HIST_FB - 1)] = y;
            out[t] = y;
        }
        __syncthreads();
    }
}

// ---------------------------------------------------------------- launch
extern "C" void kernel_launch(void* const* d_in, const int* in_sizes, int n_in,
                              void* d_out, int out_size, void* d_ws, size_t ws_size,
                              hipStream_t stream) {
    const float* delay_frames = (const float*)d_in[0];
    const float* excitation   = (const float*)d_in[1];
    const float* raw_coeff    = (const float*)d_in[2];
    const float* raw_gain     = (const float*)d_in[3];
    const float* exc_coeff    = (const float*)d_in[4];
    float* out = (float*)d_out;

    if (ws_size >= WS_TOTAL_BYTES) {
        float* ws = (float*)d_ws;
        int gridA = (T_SAMPLES + BURST + 255) / 256;
        diffks_precompute<<<gridA, 256, 0, stream>>>(delay_frames, raw_coeff,
                                                     raw_gain, exc_coeff, ws);
        diffks_serial<<<1, 256, 0, stream>>>(excitation, ws, out);
    } else {
        diffks_fallback<<<1, 128, 0, stream>>>(delay_frames, excitation,
                                               raw_coeff, raw_gain, exc_coeff, out);
    }
}

// Round 15
// 143.113 us; speedup vs baseline: 1.0247x; 1.0247x over previous
//
#include <hip/hip_runtime.h>
#include <math.h>

// DiffKS round 18 = exact revert to round 16 (the verified best: serial
// 82.7us, total 144.1us). r17's packed v_pk_fma_f32 regressed (+2.2us:
// operand-pair construction emitted v_mov shuffles costing more than the 7
// saved instructions). Both r16/r17 hit the pre-committed stop rule
// (serial >= 80us): the owner wave's serial recurrence is at the lone-wave
// ~8cy/instr issue+dependency floor (~27 instr/body x 441 bodies) plus
// ~15us of phase-0/1. All levers tested across 17 rounds: issue count
// (r12,r14,r16), round trips (r15: null), step count (r11,r13: ~40cy/step),
// packed math (r17: negative), adaptive chunking (r9,r10: negative),
// multi-wave roles (r8,r11: the structure that works). Converged.

#define T_SAMPLES 44100
#define NFRAMES   100
#define NCOEF     6
#define BURST     2048
#define EXC_ORD   5

#define HISTSZ    2120          // 2048 ring + 64 dump slots + pad
#define GRPF      9600          // 800 samples * 12 floats per group
#define CFBUF     9856          // 9728 staged (38x1KB) + 128 pad for reads
#define POOLF     32448         // 3*CFBUF (29568) / phase-1 overlay (32448)

#define WS_COEF_FLOATS (T_SAMPLES * 12)
#define WS_EXC_OFF     WS_COEF_FLOATS
#define WS_EXC_FLOATS  (EXC_ORD * BURST)
#define WS_TOTAL_BYTES ((size_t)(WS_COEF_FLOATS + WS_EXC_FLOATS) * 4)

// ---------------------------------------------------------------- kernel A
__global__ __launch_bounds__(256) void diffks_precompute(
    const float* __restrict__ delay_frames,
    const float* __restrict__ raw_coeff,
    const float* __restrict__ raw_gain,
    const float* __restrict__ exc_coeff,
    float* __restrict__ ws)
{
    int g = blockIdx.x * 256 + threadIdx.x;
    const float gain = 0.1f / (1.0f + expf(-raw_gain[0])) + 0.9f;

    if (g < T_SAMPLES) {
        const float stepT = 99.0f / (float)(T_SAMPLES - 1);
        float pos = (float)g * stepT;
        int i0 = (int)pos; if (i0 > NFRAMES - 2) i0 = NFRAMES - 2;
        float w = pos - (float)i0;

        float d0 = delay_frames[i0], d1 = delay_frames[i0 + 1];
        float delay = d0 + (d1 - d0) * w;
        int z = (int)delay;                  // delay >= 100 > 0
        float alfa = delay - (float)z;

        float b[NCOEF];
        {
            float c0v[NCOEF], c1v[NCOEF];
            float s0 = 0.f, s1 = 0.f;
            #pragma unroll
            for (int j = 0; j < NCOEF; ++j) {
                c0v[j] = 1.0f / (1.0f + expf(-raw_coeff[i0 * NCOEF + j]));
                c1v[j] = 1.0f / (1.0f + expf(-raw_coeff[(i0 + 1) * NCOEF + j]));
                s0 += c0v[j]; s1 += c1v[j];
            }
            float g0 = gain / s0, g1 = gain / s1;
            #pragma unroll
            for (int j = 0; j < NCOEF; ++j) {
                float x0 = c0v[j] * g0, x1 = c1v[j] * g1;
                b[j] = x0 + (x1 - x0) * w;
            }
        }
        // v_j exactly as previous rounds (bit-identical), then negate (exact)
        float oma = 1.0f - alfa;
        float v0 = -oma * b[0];
        float v1 = -(alfa * b[0] + oma * b[1]);
        float v2 = -(alfa * b[1] + oma * b[2]);
        float v3 = -(alfa * b[2] + oma * b[3]);
        float v4 = -(alfa * b[3] + oma * b[4]);
        float v5 = -(alfa * b[4] + oma * b[5]);
        float v6 = -alfa * b[5];
        float pv0 = -v0, pv1 = -v1, pv2 = -v2, pv3 = -v3;
        float pv4 = -v4, pv5 = -v5, pv6 = -v6;

        int base = g - z - 1;
        int q = base - 6;                    // window = y[q .. q+6]
        int off = q & 1;
        unsigned b2 = ((unsigned)q) & 2046u; // (q & ~1) & 2047, 8B-aligned

        // shifted taps: m[off+6-j] = pv_j  (FMA iterates i = 7..0)
        float m0, m1, m2, m3, m4, m5, m6, m7;
        if (off) { m0 = 0.f; m1 = pv6; m2 = pv5; m3 = pv4;
                   m4 = pv3; m5 = pv2; m6 = pv1; m7 = pv0; }
        else     { m0 = pv6; m1 = pv5; m2 = pv4; m3 = pv3;
                   m4 = pv2; m5 = pv1; m6 = pv0; m7 = 0.f; }

        float4* o = (float4*)(ws + (size_t)g * 12);
        o[0] = make_float4(m0, m1, m2, m3);
        o[1] = make_float4(m4, m5, m6, m7);
        o[2] = make_float4(__int_as_float((int)b2), 0.f, 0.f, 0.f);
    } else if (g < T_SAMPLES + BURST) {
        int te = g - T_SAMPLES;
        const float stepE = 99.0f / (float)(BURST - 1);
        float pos = (float)te * stepE;
        int i0 = (int)pos; if (i0 > NFRAMES - 2) i0 = NFRAMES - 2;
        float w = pos - (float)i0;
        float* o = ws + WS_EXC_OFF + te * EXC_ORD;     // interleaved [t*5+k]
        #pragma unroll
        for (int k = 0; k < EXC_ORD; ++k) {
            float a0 = exc_coeff[i0 * EXC_ORD + k];
            float a1 = exc_coeff[(i0 + 1) * EXC_ORD + k];
            o[k] = a0 + (a1 - a0) * w;
        }
    }
}

// async global->LDS copy, 16B per lane; LDS base must be wave-uniform
__device__ __forceinline__ void gload_lds16(const float* g, float* l) {
    __builtin_amdgcn_global_load_lds(
        (const __attribute__((address_space(1))) unsigned int*)(g),
        (__attribute__((address_space(3))) unsigned int*)(l),
        16, 0, 0);
}

// ---------------------------------------------------------------- kernel B
__global__ __launch_bounds__(256, 1) void diffks_serial(
    const float* __restrict__ excitation,
    const float* __restrict__ ws,
    float* __restrict__ out)
{
    __shared__ float s_pool[POOLF];      // 3 coef buffers / phase-1 overlay
    __shared__ float s_x[64][33];        // burst (padded rows)
    __shared__ float s_hist[HISTSZ];     // 2048 ring + 64 dump

    // phase-1 arrays overlay coef buffer 2 region (phase 1 ends before use)
    float (* const s_a)[161]   = (float(*)[161])(s_pool + 19712);
    float (* const s_tail)[32] = (float(*)[32])(s_pool + 30016);
    float (* const s_bound)[6] = (float(*)[6])(s_pool + 32064);

    const int tid  = threadIdx.x;
    const int lane = tid & 63;
    const int wv   = tid >> 6;

    // ---- stage (all 256 threads) ----
    for (int t = tid; t < BURST; t += 256)
        s_x[t >> 5][t & 31] = excitation[t];
    for (int i = 0; i < 8; ++i) {        // exc coefs, 5 contiguous scalars
        int t = tid + i * 256;
        const float* g = ws + WS_EXC_OFF + t * EXC_ORD;
        float* dst = &s_a[t >> 5][(t & 31) * 5];
        dst[0] = g[0]; dst[1] = g[1]; dst[2] = g[2];
        dst[3] = g[3]; dst[4] = g[4];
    }
    for (int i = tid; i < HISTSZ; i += 256) s_hist[i] = 0.0f;
    __syncthreads();

    // ---- phase 1: excitation LPC via 64-segment state-space scan (wave 0) --
    if (tid < 64) {
        float st[6][5];
        #pragma unroll
        for (int r = 0; r < 6; ++r)
            #pragma unroll
            for (int k = 0; k < 5; ++k) st[r][k] = 0.0f;
        #pragma unroll
        for (int r = 1; r <= 5; ++r) st[r][r - 1] = 1.0f;

        const float* ar = &s_a[lane][0];
        const float* xr = &s_x[lane][0];
        #pragma unroll 8
        for (int i = 0; i < 32; ++i) {
            float a0 = ar[i * 5 + 0], a1 = ar[i * 5 + 1], a2 = ar[i * 5 + 2];
            float a3 = ar[i * 5 + 3], a4 = ar[i * 5 + 4];
            float xv = xr[i];
            #pragma unroll
            for (int r = 0; r < 6; ++r) {
                float acc = (r == 0) ? xv : 0.0f;
                acc = fmaf(-a0, st[r][0], acc);
                acc = fmaf(-a1, st[r][1], acc);
                acc = fmaf(-a2, st[r][2], acc);
                acc = fmaf(-a3, st[r][3], acc);
                acc = fmaf(-a4, st[r][4], acc);
                st[r][4] = st[r][3]; st[r][3] = st[r][2];
                st[r][2] = st[r][1]; st[r][1] = st[r][0];
                st[r][0] = acc;
            }
        }
        #pragma unroll
        for (int r = 0; r < 6; ++r)
            #pragma unroll
            for (int k = 0; k < 5; ++k)
                s_tail[lane][r * 5 + k] = st[r][k];
    }
    __syncthreads();

    if (tid < 5) {   // boundary chain: 5 lanes, one output component each
        float Yk = 0.0f;
        for (int l = 0; l < 64; ++l) {
            s_bound[l][tid] = Yk;
            float y0 = __shfl(Yk, 0);
            float y1 = __shfl(Yk, 1);
            float y2 = __shfl(Yk, 2);
            float y3 = __shfl(Yk, 3);
            float y4 = __shfl(Yk, 4);
            const float* tl = &s_tail[l][0];
            float acc = tl[tid];
            acc = fmaf(tl[5 + tid],  y0, acc);
            acc = fmaf(tl[10 + tid], y1, acc);
            acc = fmaf(tl[15 + tid], y2, acc);
            acc = fmaf(tl[20 + tid], y3, acc);
            acc = fmaf(tl[25 + tid], y4, acc);
            Yk = acc;
        }
    }
    __syncthreads();

    if (tid < 64) {   // re-run each segment with correct boundary state
        float b0 = s_bound[lane][0], b1 = s_bound[lane][1], b2 = s_bound[lane][2];
        float b3 = s_bound[lane][3], b4 = s_bound[lane][4];
        const float* ar = &s_a[lane][0];
        float* xr = &s_x[lane][0];
        #pragma unroll 8
        for (int i = 0; i < 32; ++i) {
            float a0 = ar[i * 5 + 0], a1 = ar[i * 5 + 1], a2 = ar[i * 5 + 2];
            float a3 = ar[i * 5 + 3], a4 = ar[i * 5 + 4];
            float acc = xr[i];
            acc = fmaf(-a0, b0, acc);
            acc = fmaf(-a1, b1, acc);
            acc = fmaf(-a2, b2, acc);
            acc = fmaf(-a3, b3, acc);
            acc = fmaf(-a4, b4, acc);
            b4 = b3; b3 = b2; b2 = b1; b1 = b0; b0 = acc;
            xr[i] = acc;
        }
    }
    __syncthreads();    // phase 1 done; s_pool free for the 3 coef buffers

    // ---- phase 2: 4-wave round-robin, 8 bodies/step, 8 prepped reg sets ----
    const bool lane_act = (lane < 50);
    const unsigned dumpA = 2048u + (unsigned)lane;   // per-lane dump slot

    #define STAGE_GRP(gg)                                                      \
    {                                                                          \
        float* dstb = s_pool + ((unsigned)(gg) % 3u) * CFBUF;                  \
        const float* srcb = ws + (size_t)(gg) * GRPF + lane * 4;               \
        const int nis = ((gg) >= 55) ? 5 : 38;                                 \
        for (int i = 0; i < nis; ++i)                                          \
            gload_lds16(srcb + i * 256, dstb + i * 256);                       \
    }

    // 8 register sets, all statically named (~184 VGPR; 1 wave/SIMD has 512)
    #define DECLSET(J)                                                         \
        float4 p##J##a0, p##J##a1, p##J##b0, p##J##b1;                         \
        unsigned u##J##A0, u##J##A1, u##J##A2, u##J##A3;                       \
        unsigned u##J##B0, u##J##B1, u##J##B2, u##J##B3;                       \
        unsigned w##J##A, w##J##B;                                             \
        float x##J##A, x##J##B;
    DECLSET(0) DECLSET(1) DECLSET(2) DECLSET(3)
    DECLSET(4) DECLSET(5) DECLSET(6) DECLSET(7)
    #undef DECLSET

    #define PREPJ(J, BB, WXF)                                                  \
    {                                                                          \
        int b_ = (BB); if (b_ > 440) b_ = 440;                                 \
        const float* bu_ = s_pool + ((unsigned)(b_ >> 3) % 3u) * CFBUF;        \
        const int ln_ = (b_ & 7) * 100 + lane;                                 \
        const float4* qA_ = (const float4*)(bu_ + ln_ * 12);                   \
        const float4* qB_ = (const float4*)(bu_ + (ln_ + 50) * 12);            \
        p##J##a0 = qA_[0]; p##J##a1 = qA_[1];                                  \
        const unsigned bA_ = (unsigned)__float_as_int(qA_[2].x);               \
        p##J##b0 = qB_[0]; p##J##b1 = qB_[1];                                  \
        const unsigned bB_ = (unsigned)__float_as_int(qB_[2].x);               \
        u##J##A0 = bA_;               u##J##B0 = bB_;                          \
        u##J##A1 = (bA_ + 2) & 2047u; u##J##B1 = (bB_ + 2) & 2047u;            \
        u##J##A2 = (bA_ + 4) & 2047u; u##J##B2 = (bB_ + 4) & 2047u;            \
        u##J##A3 = (bA_ + 6) & 2047u; u##J##B3 = (bB_ + 6) & 2047u;            \
        const int tA_ = b_ * 100 + lane;                                       \
        const int tB_ = tA_ + 50;                                              \
        if (WXF) {                                                             \
            x##J##A = (lane_act && tA_ < BURST)                                \
                          ? s_x[(tA_ >> 5) & 63][tA_ & 31] : 0.0f;             \
            x##J##B = (lane_act && tB_ < BURST)                                \
                          ? s_x[(tB_ >> 5) & 63][tB_ & 31] : 0.0f;             \
        } else { x##J##A = 0.0f; x##J##B = 0.0f; }                             \
        w##J##A = lane_act ? (((unsigned)tA_) & 2047u) : dumpA;                \
        w##J##B = lane_act ? (((unsigned)tB_) & 2047u) : dumpA;                \
    }

    #define PREPALL(SS, WXF)                                                   \
    {                                                                          \
        const int nb_ = (SS) * 8;                                              \
        PREPJ(0, nb_ + 0, WXF) PREPJ(1, nb_ + 1, WXF)                          \
        PREPJ(2, nb_ + 2, WXF) PREPJ(3, nb_ + 3, WXF)                          \
        PREPJ(4, nb_ + 4, WXF) PREPJ(5, nb_ + 5, WXF)                          \
        PREPJ(6, nb_ + 6, WXF) PREPJ(7, nb_ + 7, WXF)                          \
    }

    // one body: 8 ds_read (first-used-first) -> two independent 4-deep FMA
    // chains (hi: m1 taps; lo: x + m0 taps) -> add -> 2 ds_write.
    #define CBODY(J)                                                           \
    {                                                                          \
        const float2 a67_ = *(const float2*)(s_hist + u##J##A3);               \
        const float2 b67_ = *(const float2*)(s_hist + u##J##B3);               \
        const float2 a45_ = *(const float2*)(s_hist + u##J##A2);               \
        const float2 b45_ = *(const float2*)(s_hist + u##J##B2);               \
        const float2 a23_ = *(const float2*)(s_hist + u##J##A1);               \
        const float2 b23_ = *(const float2*)(s_hist + u##J##B1);               \
        const float2 a01_ = *(const float2*)(s_hist + u##J##A0);               \
        const float2 b01_ = *(const float2*)(s_hist + u##J##B0);               \
        float hiA = p##J##a1.w * a67_.y;                                       \
        float hiB = p##J##b1.w * b67_.y;                                       \
        hiA = fmaf(p##J##a1.z, a67_.x, hiA);                                   \
        hiB = fmaf(p##J##b1.z, b67_.x, hiB);                                   \
        hiA = fmaf(p##J##a1.y, a45_.y, hiA);                                   \
        hiB = fmaf(p##J##b1.y, b45_.y, hiB);                                   \
        hiA = fmaf(p##J##a1.x, a45_.x, hiA);                                   \
        hiB = fmaf(p##J##b1.x, b45_.x, hiB);                                   \
        float loA = x##J##A, loB = x##J##B;                                    \
        loA = fmaf(p##J##a0.w, a23_.y, loA);                                   \
        loB = fmaf(p##J##b0.w, b23_.y, loB);                                   \
        loA = fmaf(p##J##a0.z, a23_.x, loA);                                   \
        loB = fmaf(p##J##b0.z, b23_.x, loB);                                   \
        loA = fmaf(p##J##a0.y, a01_.y, loA);                                   \
        loB = fmaf(p##J##b0.y, b01_.y, loB);                                   \
        loA = fmaf(p##J##a0.x, a01_.x, loA);                                   \
        loB = fmaf(p##J##b0.x, b01_.x, loB);                                   \
        s_hist[w##J##A] = loA + hiA;                                           \
        s_hist[w##J##B] = loB + hiB;                                           \
    }

    // one super-step: owner computes 8 bodies; stager issues group ss+2;
    // dumper stores previous step's 800 samples; prepper drains own vmcnt
    // and preps ALL of step ss+1.
    #define STEPBODY(WXF)                                                      \
    {                                                                          \
        if (wv == (ss & 3)) {                                                  \
            CBODY(0) CBODY(1) CBODY(2) CBODY(3)                                \
            CBODY(4) CBODY(5) CBODY(6) CBODY(7)                                \
        }                                                                      \
        if ((ss <= 53) && (wv == ((ss + 2) & 3))) { STAGE_GRP(ss + 2) }        \
        if ((ss >= 1) && (wv == ((ss + 3) & 3))) {                             \
            const int t0_ = (ss - 1) * 800;                                    \
            _Pragma("unroll")                                                  \
            for (int i_ = 0; i_ < 12; ++i_) {                                  \
                int t_ = t0_ + i_ * 64 + lane;                                 \
                out[t_] = s_hist[((unsigned)t_) & 2047u];                      \
            }                                                                  \
            { int t_ = t0_ + 768 + lane;                                       \
              if (lane < 32) out[t_] = s_hist[((unsigned)t_) & 2047u]; }       \
        }                                                                      \
        if (wv == ((ss + 1) & 3)) {                                            \
            asm volatile("s_waitcnt vmcnt(0)" ::: "memory");                   \
            PREPALL(ss + 1, WXF)                                               \
        }                                                                      \
        asm volatile("s_waitcnt lgkmcnt(0)\n\ts_barrier" ::: "memory");        \
    }

    // prologue: wave 0 stages+drains group 0 and preps step 0 (bodies 0..7);
    // wave 1 stages group 1 (drains own vmcnt at step 0 as prepper).
    if (wv == 0) {
        STAGE_GRP(0)
        asm volatile("s_waitcnt vmcnt(0)" ::: "memory");
    }
    if (wv == 1) { STAGE_GRP(1) }
    __syncthreads();
    if (wv == 0) { PREPALL(0, true) }
    __syncthreads();

    // steps 0..1: preps still excitation-active (bodies 8..23 cover body 20)
    #pragma unroll 1
    for (int ss = 0; ss < 2; ++ss) STEPBODY(true)
    // steps 2..54: steady state (prepped bodies >= 24, t >= 2400 > 2047)
    #pragma unroll 1
    for (int ss = 2; ss < 55; ++ss) STEPBODY(false)

    // tail body 440 (step 55, owner wave 3, set 0 prepped at step 54)
    if (wv == 3) { CBODY(0) }
    asm volatile("s_waitcnt lgkmcnt(0)\n\ts_barrier" ::: "memory");
    // final dump: samples [43200, 44100)
    for (int t_ = 43200 + tid; t_ < T_SAMPLES; t_ += 256)
        out[t_] = s_hist[((unsigned)t_) & 2047u];

    #undef STEPBODY
    #undef CBODY
    #undef PREPALL
    #undef PREPJ
    #undef STAGE_GRP
}

// ------------------------------------------------- fallback (round-1 kernel)
#define CHUNK_FB  101
#define NCH_FB    ((T_SAMPLES + CHUNK_FB - 1) / CHUNK_FB)
#define HIST_FB   1024

__global__ __launch_bounds__(128) void diffks_fallback(
    const float* __restrict__ delay_frames,
    const float* __restrict__ excitation,
    const float* __restrict__ raw_coeff,
    const float* __restrict__ raw_gain,
    const float* __restrict__ exc_coeff,
    float* __restrict__ out)
{
    __shared__ float s_a[EXC_ORD][BURST];
    __shared__ float s_x[BURST];
    __shared__ float s_hist[HIST_FB];
    __shared__ __align__(16) float s_coef[NFRAMES][8];
    __shared__ float s_delay[NFRAMES];

    const int tid = threadIdx.x;
    const float gain = 0.1f / (1.0f + expf(-raw_gain[0])) + 0.9f;

    for (int i = tid; i < NFRAMES; i += 128) s_delay[i] = delay_frames[i];
    for (int f = tid; f < NFRAMES; f += 128) {
        float sb[NCOEF]; float s = 0.0f;
        #pragma unroll
        for (int j = 0; j < NCOEF; ++j) {
            sb[j] = 1.0f / (1.0f + expf(-raw_coeff[f * NCOEF + j]));
            s += sb[j];
        }
        float inv = gain / s;
        #pragma unroll
        for (int j = 0; j < NCOEF; ++j) s_coef[f][j] = sb[j] * inv;
        s_coef[f][6] = 0.0f; s_coef[f][7] = 0.0f;
    }
    const float stepE = 99.0f / 2047.0f;
    for (int t = tid; t < BURST; t += 128) {
        float pos = (float)t * stepE;
        int i0 = (int)pos; if (i0 > NFRAMES - 2) i0 = NFRAMES - 2;
        float w = pos - (float)i0;
        const float* c0 = exc_coeff + i0 * EXC_ORD;
        #pragma unroll
        for (int k = 0; k < EXC_ORD; ++k) {
            float a0 = c0[k], a1 = c0[k + EXC_ORD];
            s_a[k][t] = a0 + (a1 - a0) * w;
        }
        s_x[t] = excitation[t];
    }
    for (int i = tid; i < HIST_FB; i += 128) s_hist[i] = 0.0f;
    __syncthreads();

    if (tid == 0) {
        float y1 = 0.f, y2 = 0.f, y3 = 0.f, y4 = 0.f, y5 = 0.f;
        #pragma unroll 4
        for (int t = 0; t < BURST; ++t) {
            float p = s_x[t];
            p = fmaf(-s_a[1][t], y2, p);
            p = fmaf(-s_a[2][t], y3, p);
            p = fmaf(-s_a[3][t], y4, p);
            p = fmaf(-s_a[4][t], y5, p);
            float y = fmaf(-s_a[0][t], y1, p);
            s_x[t] = y;
            y5 = y4; y4 = y3; y3 = y2; y2 = y1; y1 = y;
        }
    }
    __syncthreads();

    const float stepT = 99.0f / (float)(T_SAMPLES - 1);
    for (int c = 0; c < NCH_FB; ++c) {
        int t = c * CHUNK_FB + tid;
        if (tid < CHUNK_FB && t < T_SAMPLES) {
            float pos = (float)t * stepT;
            int i0 = (int)pos; if (i0 > NFRAMES - 2) i0 = NFRAMES - 2;
            float w = pos - (float)i0;
            float d0 = s_delay[i0], d1 = s_delay[i0 + 1];
            float delay = d0 + (d1 - d0) * w;
            int z = (int)delay;
            float alfa = delay - (float)z;
            const float4* f0 = reinterpret_cast<const float4*>(s_coef[i0]);
            const float4* f1 = reinterpret_cast<const float4*>(s_coef[i0 + 1]);
            float4 c0a = f0[0], c0b = f0[1];
            float4 c1a = f1[0], c1b = f1[1];
            float b[NCOEF];
            b[0] = c0a.x + (c1a.x - c0a.x) * w;
            b[1] = c0a.y + (c1a.y - c0a.y) * w;
            b[2] = c0a.z + (c1a.z - c0a.z) * w;
            b[3] = c0a.w + (c1a.w - c0a.w) * w;
            b[4] = c0b.x + (c1b.x - c0b.x) * w;
            b[5] = c0b.y + (c1b.y - c0b.y) * w;
            float oma = 1.0f - alfa;
            float v[7];
            v[0] = -oma * b[0];
            #pragma unroll
            for (int j = 1; j <= 5; ++j) v[j] = -(alfa * b[j - 1] + oma * b[j]);
            v[6] = -alfa * b[5];
            float x = (t < BURST) ? s_x[t] : 0.0f;
            int base = t - z - 1;
            float sum = 0.0f;
            #pragma unroll
            for (int j = 0; j < 7; ++j) {
                int idx = base - j;
                float yv = s_hist[idx & (HIST_FB - 1)];
                if (idx < 0) yv = 0.0f;
                sum = fmaf(v[j], yv, sum);
            }
            float y = x - sum;
            s_hist[t & (HIST_FB - 1)] = y;
            out[t] = y;
        }
        __syncthreads();
    }
}

// ---------------------------------------------------------------- launch
extern "C" void kernel_launch(void* const* d_in, const int* in_sizes, int n_in,
                              void* d_out, int out_size, void* d_ws, size_t ws_size,
                              hipStream_t stream) {
    const float* delay_frames = (const float*)d_in[0];
    const float* excitation   = (const float*)d_in[1];
    const float* raw_coeff    = (const float*)d_in[2];
    const float* raw_gain     = (const float*)d_in[3];
    const float* exc_coeff    = (const float*)d_in[4];
    float* out = (float*)d_out;

    if (ws_size >= WS_TOTAL_BYTES) {
        float* ws = (float*)d_ws;
        int gridA = (T_SAMPLES + BURST + 255) / 256;
        diffks_precompute<<<gridA, 256, 0, stream>>>(delay_frames, raw_coeff,
                                                     raw_gain, exc_coeff, ws);
        diffks_serial<<<1, 256, 0, stream>>>(excitation, ws, out);
    } else {
        diffks_fallback<<<1, 128, 0, stream>>>(delay_frames, excitation,
                                               raw_coeff, raw_gain, exc_coeff, out);
    }
}